// Round 10
// baseline (580.414 us; speedup 1.0000x reference)
//
#include <hip/hip_runtime.h>
#include <hip/hip_bf16.h>
#include <math.h>

typedef __bf16 bf16_t;
typedef __bf16 bf16x8 __attribute__((ext_vector_type(8)));
typedef __bf16 bf16x4 __attribute__((ext_vector_type(4)));
typedef float  f32x4  __attribute__((ext_vector_type(4)));

#define B_   8
#define L_   1024
#define D_   512
#define H_   8
#define HD_  4096   // H*D
#define BL_  8192   // B*L
#define KOFF 33554432L   // kh - qh in bf16 elems (64 MiB); fixed by ws layout

__device__ __forceinline__ void gload_lds16(const bf16_t* g, bf16_t* l) {
  __builtin_amdgcn_global_load_lds(
      (const __attribute__((address_space(1))) unsigned int*)g,
      (__attribute__((address_space(3))) unsigned int*)l,
      16, 0, 0);
}

// XCD-bijective remap (m204): XCD (=lin%8) owns a contiguous band of virt ids.
// Requires nwg % 8 == 0 (all our grids comply). Bijective -> correctness-neutral.
__device__ __forceinline__ void xcd_remap(int& tx, int& ty, int& tz) {
  const int nwg = gridDim.x * gridDim.y * gridDim.z;
  const int lin = blockIdx.x + gridDim.x * (blockIdx.y + gridDim.y * blockIdx.z);
  const int virt = (lin & 7) * (nwg >> 3) + (lin >> 3);
  tx = virt % gridDim.x;
  const int rem = virt / gridDim.x;
  ty = rem % gridDim.y;
  tz = rem / gridDim.y;
}

// ---- prep: fp32->bf16 q/k/v convert (z 0-2) + weight transpose+convert (z 3-6) ----
__global__ void prep(const float4* __restrict__ q, const float4* __restrict__ k,
                     const float4* __restrict__ v, bf16x4* __restrict__ qo,
                     bf16x4* __restrict__ ko, bf16x4* __restrict__ vo,
                     const float* __restrict__ wq, const float* __restrict__ wk,
                     const float* __restrict__ wv, const float* __restrict__ wfc,
                     bf16_t* __restrict__ wqT, bf16_t* __restrict__ wkT,
                     bf16_t* __restrict__ wvT, bf16_t* __restrict__ wfT) {
  __shared__ float t[32][33];
  const int z = blockIdx.z;
  if (z < 3) {
    const float4* s = (z == 0) ? q : (z == 1) ? k : v;
    bf16x4* d = (z == 0) ? qo : (z == 1) ? ko : vo;
    const int tid = threadIdx.y * 32 + threadIdx.x;
    const int base = (blockIdx.y * 128 + blockIdx.x) * 256 + tid;   // 2048 blocks
    #pragma unroll
    for (int o = 0; o < 2; ++o) {                                   // n4 = 1048576
      const int i = base + o * 524288;
      float4 x = s[i];
      bf16x4 oo;
      oo[0] = (bf16_t)x.x; oo[1] = (bf16_t)x.y;
      oo[2] = (bf16_t)x.z; oo[3] = (bf16_t)x.w;
      d[i] = oo;
    }
    return;
  }
  const int zz = z - 3;
  const float* s; bf16_t* d; int R, C, c0, r0;
  if (zz < 3) {
    s = (zz == 0) ? wq : (zz == 1) ? wk : wv;
    d = (zz == 0) ? wqT : (zz == 1) ? wkT : wvT;
    R = D_; C = HD_; c0 = blockIdx.x * 32; r0 = blockIdx.y * 32;
  } else {
    s = wfc; d = wfT;
    R = HD_; C = D_; c0 = blockIdx.y * 32; r0 = blockIdx.x * 32;
  }
  const int tx = threadIdx.x, ty = threadIdx.y;
  #pragma unroll
  for (int i = 0; i < 32; i += 8)
    t[ty + i][tx] = s[(long)(r0 + ty + i) * C + c0 + tx];
  __syncthreads();
  #pragma unroll
  for (int i = 0; i < 32; i += 8)
    d[(long)(c0 + ty + i) * R + r0 + tx] = (bf16_t)t[tx][ty + i];
}

// ================= 256x256 8-phase GEMM, A(M,K) x Bt(N,K)^T =================
// EPI 0: bf16 store; EPI 1: f32 store;
// EPI 4: merged QKV — A selected per n-tile (qbf/kbf/vbf via sAb stride);
//        n-tile<16: qh (scaled), <32: kh, else vhT transposed store (Cv2).
#define VM4 asm volatile("s_waitcnt vmcnt(4)" ::: "memory")
#define VM0 asm volatile("s_waitcnt vmcnt(0)" ::: "memory")

#define STG(OP, BUF, KK, TILE) do { \
  const bf16_t* gsrc_ = (OP) ? Bg : Ag; \
  const long gld_ = (OP) ? ldb : lda; \
  bf16_t* lb_ = lds + (BUF)*32768 + (OP)*16384 + (KK)*8192 + wid*512; \
  gload_lds16(gsrc_ + (long)(TILE)*64 + (KK)*32, lb_); \
  gload_lds16(gsrc_ + (long)128*gld_ + (long)(TILE)*64 + (KK)*32, lb_ + 4096); \
} while (0)

#define LDA(I, BUF, KK) (*(const bf16x8*)(lds + (BUF)*32768 + (KK)*8192 + offA[I]))
#define LDB(J, BUF, KK) (*(const bf16x8*)(lds + (BUF)*32768 + 16384 + (KK)*8192 + offB[J]))

#define MM(q, ii, jj) acc[(q)*4+(ii)][(jj)] = \
  __builtin_amdgcn_mfma_f32_16x16x32_bf16(a##ii, b##jj, acc[(q)*4+(ii)][(jj)], 0, 0, 0)

#define PHASE(Q, KK, BUF, STAGE, VM) do { \
  bf16x8 a0, a1, a2, a3; \
  if ((Q) == 0) { b0 = LDB(0,BUF,KK); b1 = LDB(1,BUF,KK); b2 = LDB(2,BUF,KK); b3 = LDB(3,BUF,KK); } \
  a0 = LDA((Q)*4+0,BUF,KK); a1 = LDA((Q)*4+1,BUF,KK); \
  a2 = LDA((Q)*4+2,BUF,KK); a3 = LDA((Q)*4+3,BUF,KK); \
  STAGE; \
  __builtin_amdgcn_s_barrier(); \
  asm volatile("s_waitcnt lgkmcnt(0)" ::: "memory"); \
  __builtin_amdgcn_sched_barrier(0); \
  __builtin_amdgcn_s_setprio(1); \
  MM(Q,0,0); MM(Q,1,0); MM(Q,2,0); MM(Q,3,0); \
  MM(Q,0,1); MM(Q,1,1); MM(Q,2,1); MM(Q,3,1); \
  MM(Q,0,2); MM(Q,1,2); MM(Q,2,2); MM(Q,3,2); \
  MM(Q,0,3); MM(Q,1,3); MM(Q,2,3); MM(Q,3,3); \
  __builtin_amdgcn_s_setprio(0); \
  VM; \
  __builtin_amdgcn_s_barrier(); \
} while (0)

template<int EPI>
__launch_bounds__(512, 2)
__global__ void gemm256(const bf16_t* __restrict__ A, long sAb, long sAh, int lda,
                        const bf16_t* __restrict__ Bt, long sBb, long sBh, int ldb,
                        void* __restrict__ Cv, long sCb, long sCh, int ldc,
                        int K, float scale, void* __restrict__ Cv2)
{
  __shared__ __align__(16) bf16_t lds[65536];   // 128 KiB
  int tx, ty, tz;
  xcd_remap(tx, ty, tz);
  const int bz = tz, b = bz >> 3, h = bz & 7;
  if (EPI == 4) {
    A += (long)((tx >= 32) ? 2 : (tx >= 16) ? 1 : 0) * sAb;
  } else {
    A += (long)b * sAb + (long)h * sAh;
  }
  Bt += (long)b * sBb + (long)h * sBh;
  const int m0 = ty * 256, n0 = tx * 256;
  const int tid = threadIdx.x, lane = tid & 63, wid = tid >> 6;
  const int wm = wid >> 2, wn = wid & 3;

  const int srow  = tid >> 2;
  const int sslot = (lane & 3) ^ ((tid >> 3) & 3);
  const bf16_t* Ag = A + (long)(m0 + srow) * lda + sslot * 8;
  const bf16_t* Bg = Bt + (long)(n0 + srow) * ldb + sslot * 8;

  int offA[8], offB[4];
  #pragma unroll
  for (int i = 0; i < 8; ++i) {
    const int r = wm * 128 + i * 16 + (lane & 15);
    offA[i] = r * 32 + (((lane >> 4) ^ ((r >> 1) & 3)) * 8);
  }
  #pragma unroll
  for (int j = 0; j < 4; ++j) {
    const int r = wn * 64 + j * 16 + (lane & 15);
    offB[j] = r * 32 + (((lane >> 4) ^ ((r >> 1) & 3)) * 8);
  }

  f32x4 acc[8][4] = {};
  const int ITER = K >> 7;

  STG(0,0,0,0); STG(0,0,1,0); STG(1,0,0,0); STG(1,0,1,0);
  STG(0,1,0,1); STG(1,1,0,1);
  VM4;
  __builtin_amdgcn_s_barrier();

  for (int i = 0; i < ITER; ++i) {
    const int t = 2 * i;
    const bool stg = (i + 1 < ITER);
    bf16x8 b0, b1, b2, b3;
    PHASE(0,0,0, STG(0,1,1,t+1);                , (void)0);
    PHASE(1,0,0, STG(1,1,1,t+1);                , (void)0);
    PHASE(0,1,0, { if (stg) STG(0,0,0,t+2); }   , (void)0);
    PHASE(1,1,0, { if (stg) STG(1,0,0,t+2); }   , { if (stg) { VM4; } else { VM0; } });
    PHASE(0,0,1, { if (stg) STG(0,0,1,t+2); }   , (void)0);
    PHASE(1,0,1, { if (stg) STG(1,0,1,t+2); }   , (void)0);
    PHASE(0,1,1, { if (stg) STG(0,1,0,t+3); }   , (void)0);
    PHASE(1,1,1, { if (stg) STG(1,1,0,t+3); }   , { if (stg) { VM4; } });
  }

  const float sc = (EPI == 4 && tx >= 16) ? 1.0f : scale;
  const long coff = (long)b * sCb + (long)h * sCh;
  #pragma unroll
  for (int i = 0; i < 8; ++i) {
    const int rbase = m0 + wm * 128 + i * 16 + ((lane >> 4) << 2);
    #pragma unroll
    for (int j = 0; j < 4; ++j) {
      const int c = n0 + wn * 64 + j * 16 + (lane & 15);
      if (EPI == 4) {
        if (tx < 32) {          // q or k: linear bf16 store, ld = HD_
          bf16_t* dst = (bf16_t*)Cv + (tx >= 16 ? KOFF : 0);
          const int cc = c - (tx >= 16 ? 4096 : 0);
          #pragma unroll
          for (int r = 0; r < 4; ++r)
            dst[(long)(rbase + r) * HD_ + cc] = (bf16_t)(acc[i][j][r] * sc);
        } else {                // v: transposed per-(b,h) store into vhT
          const int cc = c - 8192;
          const int b2 = rbase >> 10, l2 = rbase & 1023;
          const int h2 = cc >> 9, d2 = cc & 511;
          bf16x4 o4;
          #pragma unroll
          for (int r = 0; r < 4; ++r) o4[r] = (bf16_t)acc[i][j][r];
          *(bf16x4*)((bf16_t*)Cv2 + (long)(b2 * 8 + h2) * D_ * L_ + (long)d2 * L_ + l2) = o4;
        }
      } else {
        #pragma unroll
        for (int r = 0; r < 4; ++r) {
          float vv = acc[i][j][r] * sc;
          long idx = coff + (long)(rbase + r) * ldc + c;
          if (EPI == 0) ((bf16_t*)Cv)[idx] = (bf16_t)vv;
          else          ((float*)Cv)[idx] = vv;
        }
      }
    }
  }
}

// ---------------- bf16 GEMM, 2-barrier, BMxBN tile (out-proj) ----------------
template<int BM, int BN, int EPI>
__launch_bounds__(256, 2)
__global__ void gemm_bt(const bf16_t* __restrict__ A, long sAb, long sAh, int lda,
                        const bf16_t* __restrict__ Bt, long sBb, long sBh, int ldb,
                        void* __restrict__ Cv, long sCb, long sCh, int ldc,
                        int K, float scale, const float* __restrict__ res)
{
  constexpr int WN    = (BN == 128) ? 2 : 1;
  constexpr int SPANM = BM / (4 / WN);
  constexpr int MI    = SPANM / 16;
  constexpr int NJ    = 4;
  __shared__ bf16_t sA[BM * 64];
  __shared__ bf16_t sB[BN * 64];
  int tx, ty, tz;
  xcd_remap(tx, ty, tz);
  const int bz = tz, b = bz >> 3, h = bz & 7;
  A  += (long)b * sAb + (long)h * sAh;
  Bt += (long)b * sBb + (long)h * sBh;
  const int m0 = ty * BM, n0 = tx * BN;
  const int tid = threadIdx.x, lane = tid & 63, wid = tid >> 6;
  const int waveM = (WN == 2) ? (wid >> 1) : wid;
  const int waveN = (WN == 2) ? (wid & 1) : 0;
  f32x4 acc[MI][NJ] = {};
  const int srow = wid * 8 + (lane >> 3);
  const int skin = (lane & 7) * 8;
  const bf16_t* Ag = A + (long)(m0 + srow) * lda + skin;
  const bf16_t* Bg = Bt + (long)(n0 + srow) * ldb + skin;
  for (int k0 = 0; k0 < K; k0 += 64) {
    #pragma unroll
    for (int j = 0; j < BM / 32; ++j)
      gload_lds16(Ag + (long)(j * 32) * lda + k0, sA + (j * 4 + wid) * 512);
    #pragma unroll
    for (int j = 0; j < BN / 32; ++j)
      gload_lds16(Bg + (long)(j * 32) * ldb + k0, sB + (j * 4 + wid) * 512);
    __syncthreads();
    #pragma unroll
    for (int kk = 0; kk < 2; ++kk) {
      bf16x8 af[MI], bfr[NJ];
      #pragma unroll
      for (int i = 0; i < MI; ++i)
        af[i]  = *(const bf16x8*)(sA + (waveM * SPANM + i * 16 + (lane & 15)) * 64 + kk * 32 + ((lane >> 4) * 8));
      #pragma unroll
      for (int j = 0; j < NJ; ++j)
        bfr[j] = *(const bf16x8*)(sB + (waveN * 64 + j * 16 + (lane & 15)) * 64 + kk * 32 + ((lane >> 4) * 8));
      #pragma unroll
      for (int i = 0; i < MI; ++i)
        #pragma unroll
        for (int j = 0; j < NJ; ++j)
          acc[i][j] = __builtin_amdgcn_mfma_f32_16x16x32_bf16(af[i], bfr[j], acc[i][j], 0, 0, 0);
    }
    __syncthreads();
  }
  const long coff = (long)b * sCb + (long)h * sCh;
  #pragma unroll
  for (int i = 0; i < MI; ++i) {
    const int rbase = m0 + waveM * SPANM + i * 16 + ((lane >> 4) << 2);
    #pragma unroll
    for (int j = 0; j < NJ; ++j) {
      const int c = n0 + waveN * 64 + j * 16 + (lane & 15);
      #pragma unroll
      for (int r = 0; r < 4; ++r) {
        float v = acc[i][j][r] * scale;
        long idx = coff + (long)(rbase + r) * ldc + c;
        if (EPI == 0)      ((bf16_t*)Cv)[idx] = (bf16_t)v;
        else if (EPI == 1) ((float*)Cv)[idx] = v;
        else               ((float*)Cv)[idx] = v + res[(long)(rbase + r) * ldc + c];
      }
    }
  }
}

// ------- softmax from bf16 raw scores: write f32 attn (nt) + bf16 P in place -------
__global__ void softmax_bf16(bf16_t* __restrict__ braw, float* __restrict__ attn) {
  const long row = (long)blockIdx.x * 4 + (threadIdx.x >> 6);
  const int lane = threadIdx.x & 63;
  bf16_t* p = braw + row * 1024;
  float* ao = attn + row * 1024;
  float v[16];
  float m = -1e30f;
  #pragma unroll
  for (int j = 0; j < 2; ++j) {
    bf16x8 x = *(const bf16x8*)(p + j * 512 + lane * 8);
    #pragma unroll
    for (int e = 0; e < 8; ++e) {
      v[j * 8 + e] = (float)x[e];
      m = fmaxf(m, v[j * 8 + e]);
    }
  }
  #pragma unroll
  for (int o = 32; o; o >>= 1) m = fmaxf(m, __shfl_xor(m, o));
  float s = 0.f;
  #pragma unroll
  for (int e = 0; e < 16; ++e) { v[e] = __expf(v[e] - m); s += v[e]; }
  #pragma unroll
  for (int o = 32; o; o >>= 1) s += __shfl_xor(s, o);
  const float inv = 1.f / s;
  #pragma unroll
  for (int j = 0; j < 2; ++j) {
    bf16x8 o8;
    f32x4 f0, f1;
    f0[0] = v[j*8+0] * inv; f0[1] = v[j*8+1] * inv;
    f0[2] = v[j*8+2] * inv; f0[3] = v[j*8+3] * inv;
    f1[0] = v[j*8+4] * inv; f1[1] = v[j*8+5] * inv;
    f1[2] = v[j*8+6] * inv; f1[3] = v[j*8+7] * inv;
    o8[0] = (bf16_t)f0[0]; o8[1] = (bf16_t)f0[1]; o8[2] = (bf16_t)f0[2]; o8[3] = (bf16_t)f0[3];
    o8[4] = (bf16_t)f1[0]; o8[5] = (bf16_t)f1[1]; o8[6] = (bf16_t)f1[2]; o8[7] = (bf16_t)f1[3];
    f32x4* a4 = (f32x4*)(ao + j * 512 + lane * 8);
    __builtin_nontemporal_store(f0, a4);
    __builtin_nontemporal_store(f1, a4 + 1);
    *(bf16x8*)(p + j * 512 + lane * 8) = o8;
  }
}

// ---------------- softmax from f32 scores (fallback path) ----------------
__global__ void softmax_rows(float* __restrict__ attn, bf16_t* __restrict__ abf) {
  const long row = (long)blockIdx.x * 4 + (threadIdx.x >> 6);
  const int lane = threadIdx.x & 63;
  float* p = attn + row * 1024;
  float4 v[4];
  float m = -1e30f;
  #pragma unroll
  for (int j = 0; j < 4; ++j) {
    v[j] = ((const float4*)p)[j * 64 + lane];
    m = fmaxf(m, fmaxf(fmaxf(v[j].x, v[j].y), fmaxf(v[j].z, v[j].w)));
  }
  #pragma unroll
  for (int o = 32; o; o >>= 1) m = fmaxf(m, __shfl_xor(m, o));
  float s = 0.f;
  #pragma unroll
  for (int j = 0; j < 4; ++j) {
    v[j].x = expf(v[j].x - m); v[j].y = expf(v[j].y - m);
    v[j].z = expf(v[j].z - m); v[j].w = expf(v[j].w - m);
    s += v[j].x + v[j].y + v[j].z + v[j].w;
  }
  #pragma unroll
  for (int o = 32; o; o >>= 1) s += __shfl_xor(s, o);
  const float inv = 1.f / s;
  bf16x4* ab = (bf16x4*)(abf + row * 1024);
  #pragma unroll
  for (int j = 0; j < 4; ++j) {
    v[j].x *= inv; v[j].y *= inv; v[j].z *= inv; v[j].w *= inv;
    ((float4*)p)[j * 64 + lane] = v[j];
    bf16x4 o4;
    o4[0] = (bf16_t)v[j].x; o4[1] = (bf16_t)v[j].y;
    o4[2] = (bf16_t)v[j].z; o4[3] = (bf16_t)v[j].w;
    ab[j * 64 + lane] = o4;
  }
}

// ---------------- LayerNorm: one wave per 512-col row, in-place ----------------
__global__ void ln_rows(float* __restrict__ o, const float* __restrict__ g,
                        const float* __restrict__ be) {
  const long row = (long)blockIdx.x * 4 + (threadIdx.x >> 6);
  const int lane = threadIdx.x & 63;
  float* p = o + row * 512;
  f32x4 a = ((const f32x4*)p)[lane];
  f32x4 b = ((const f32x4*)p)[lane + 64];
  float s  = a[0] + a[1] + a[2] + a[3] + b[0] + b[1] + b[2] + b[3];
  float s2 = a[0]*a[0] + a[1]*a[1] + a[2]*a[2] + a[3]*a[3]
           + b[0]*b[0] + b[1]*b[1] + b[2]*b[2] + b[3]*b[3];
  #pragma unroll
  for (int t = 32; t; t >>= 1) { s += __shfl_xor(s, t); s2 += __shfl_xor(s2, t); }
  const float mu  = s * (1.f / 512.f);
  const float var = s2 * (1.f / 512.f) - mu * mu;
  const float inv = rsqrtf(var + 1e-6f);
  f32x4 g0 = ((const f32x4*)g)[lane],  g1 = ((const f32x4*)g)[lane + 64];
  f32x4 b0 = ((const f32x4*)be)[lane], b1 = ((const f32x4*)be)[lane + 64];
  #pragma unroll
  for (int e = 0; e < 4; ++e) {
    a[e] = (a[e] - mu) * inv * g0[e] + b0[e];
    b[e] = (b[e] - mu) * inv * g1[e] + b1[e];
  }
  __builtin_nontemporal_store(a, (f32x4*)p + lane);
  __builtin_nontemporal_store(b, (f32x4*)p + lane + 64);
}

extern "C" void kernel_launch(void* const* d_in, const int* in_sizes, int n_in,
                              void* d_out, int out_size, void* d_ws, size_t ws_size,
                              hipStream_t stream) {
  const float* q   = (const float*)d_in[0];
  const float* k   = (const float*)d_in[1];
  const float* v   = (const float*)d_in[2];
  const float* wq  = (const float*)d_in[3];
  const float* wk  = (const float*)d_in[4];
  const float* wv  = (const float*)d_in[5];
  const float* wfc = (const float*)d_in[6];
  const float* lng = (const float*)d_in[7];
  const float* lnb = (const float*)d_in[8];

  float* out   = (float*)d_out;
  float* attnf = out + (long)BL_ * D_;   // attn output region (B,H,L,L) f32

  char* ws = (char*)d_ws;
  const long MB = 1024 * 1024;
  bf16_t* qbf = (bf16_t*)(ws +   0 * MB);   // qbf/kbf/vbf contiguous, 8 MiB each
  bf16_t* kbf = (bf16_t*)(ws +   8 * MB);
  bf16_t* vbf = (bf16_t*)(ws +  16 * MB);
  bf16_t* wqT = (bf16_t*)(ws +  24 * MB);   // wqT/wkT/wvT contiguous (12288 x 512)
  bf16_t* wkT = (bf16_t*)(ws +  28 * MB);
  bf16_t* wvT = (bf16_t*)(ws +  32 * MB);
  bf16_t* wfT = (bf16_t*)(ws +  36 * MB);
  bf16_t* qh  = (bf16_t*)(ws +  40 * MB);   // 64 MiB; kh = qh + KOFF
  bf16_t* kh  = (bf16_t*)(ws + 104 * MB);   // 64 MiB
  bf16_t* vh  = (bf16_t*)(ws + 168 * MB);   // 64 MiB (ctx)
  bf16_t* vhT = (bf16_t*)(ws + 232 * MB);   // 64 MiB
  bf16_t* ctx = vh;

  const bool fused = (ws_size >= (size_t)(424 * MB));
  bf16_t* braw = (bf16_t*)(ws + 296 * MB);  // 128 MiB raw scores / P (fused path)
  bf16_t* abf  = fused ? braw : qh;         // fallback P overlays qh+kh

  // 1) prep: converts + weight transposes in ONE launch
  prep<<<dim3(128, 16, 7), dim3(32, 8), 0, stream>>>(
      (const float4*)q, (const float4*)k, (const float4*)v,
      (bf16x4*)qbf, (bf16x4*)kbf, (bf16x4*)vbf,
      wq, wk, wv, wfc, wqT, wkT, wvT, wfT);

  // 2) merged q/k/v projection: one launch, N=12288 (wqT|wkT|wvT stacked).
  const float qscale = 1.0f / sqrtf((float)D_);
  gemm256<4><<<dim3(48, 32, 1), 512, 0, stream>>>(qbf, 4194304L, 0, D_,
                                                  wqT, 0, 0, D_,
                                                  qh, 0, 0, HD_, D_, qscale, vhT);

  if (fused) {
    // 3) scores -> bf16 raw; softmax reads bf16, writes f32 attn (nt) + bf16 P
    gemm256<0><<<dim3(4, 4, B_ * H_), 512, 0, stream>>>(
        qh, (long)L_ * HD_, D_, HD_,
        kh, (long)L_ * HD_, D_, HD_,
        braw, (long)H_ * L_ * L_, (long)L_ * L_, L_, D_, 1.0f, nullptr);
    softmax_bf16<<<dim3(B_ * H_ * L_ / 4), 256, 0, stream>>>(braw, attnf);
  } else {
    gemm256<1><<<dim3(4, 4, B_ * H_), 512, 0, stream>>>(
        qh, (long)L_ * HD_, D_, HD_,
        kh, (long)L_ * HD_, D_, HD_,
        attnf, (long)H_ * L_ * L_, (long)L_ * L_, L_, D_, 1.0f, nullptr);
    softmax_rows<<<dim3(B_ * H_ * L_ / 4), 256, 0, stream>>>(attnf, abf);
  }

  // 4) ctx = P @ vhT^T per (b,h)
  gemm256<0><<<dim3(2, 4, B_ * H_), 512, 0, stream>>>(
      abf, (long)H_ * L_ * L_, (long)L_ * L_, L_,
      vhT, (long)H_ * D_ * L_, (long)D_ * L_, L_,
      ctx, (long)L_ * HD_, D_, HD_, L_, 1.0f, nullptr);

  // 5) out = ctx @ w_fc + residual(q), f32
  gemm_bt<128,64,2><<<dim3(8, 64, 1), 256, 0, stream>>>(
      ctx, 0, 0, HD_, wfT, 0, 0, HD_,
      out, 0, 0, D_, HD_, 1.0f, q);

  // 6) LayerNorm in place
  ln_rows<<<dim3(BL_ / 4), 256, 0, stream>>>(out, lng, lnb);
}

// Round 11
// 556.813 us; speedup vs baseline: 1.0424x; 1.0424x over previous
//
#include <hip/hip_runtime.h>
#include <hip/hip_bf16.h>
#include <math.h>

typedef __bf16 bf16_t;
typedef __bf16 bf16x8 __attribute__((ext_vector_type(8)));
typedef __bf16 bf16x4 __attribute__((ext_vector_type(4)));
typedef float  f32x4  __attribute__((ext_vector_type(4)));

#define B_   8
#define L_   1024
#define D_   512
#define H_   8
#define HD_  4096   // H*D
#define BL_  8192   // B*L
#define KOFF 33554432L   // kh - qh in bf16 elems (64 MiB); fixed by ws layout

__device__ __forceinline__ void gload_lds16(const bf16_t* g, bf16_t* l) {
  __builtin_amdgcn_global_load_lds(
      (const __attribute__((address_space(1))) unsigned int*)g,
      (__attribute__((address_space(3))) unsigned int*)l,
      16, 0, 0);
}

// XCD-bijective remap (m204): XCD (=lin%8) owns a contiguous band of virt ids.
// Requires nwg % 8 == 0 (all our grids comply). Bijective -> correctness-neutral.
__device__ __forceinline__ void xcd_remap(int& tx, int& ty, int& tz) {
  const int nwg = gridDim.x * gridDim.y * gridDim.z;
  const int lin = blockIdx.x + gridDim.x * (blockIdx.y + gridDim.y * blockIdx.z);
  const int virt = (lin & 7) * (nwg >> 3) + (lin >> 3);
  tx = virt % gridDim.x;
  const int rem = virt / gridDim.x;
  ty = rem % gridDim.y;
  tz = rem / gridDim.y;
}

// ---------------- fp32 -> bf16 convert, q/k/v in one launch ----------------
__global__ void f2b3(const float4* __restrict__ q, const float4* __restrict__ k,
                     const float4* __restrict__ v, bf16x4* __restrict__ qo,
                     bf16x4* __restrict__ ko, bf16x4* __restrict__ vo, int n4) {
  int i = blockIdx.x * blockDim.x + threadIdx.x;
  if (i >= n4) return;
  const float4* s = (blockIdx.y == 0) ? q : (blockIdx.y == 1) ? k : v;
  bf16x4* d = (blockIdx.y == 0) ? qo : (blockIdx.y == 1) ? ko : vo;
  float4 x = s[i];
  bf16x4 o;
  o[0] = (bf16_t)x.x; o[1] = (bf16_t)x.y; o[2] = (bf16_t)x.z; o[3] = (bf16_t)x.w;
  d[i] = o;
}

// ------- transpose + convert all 4 weights in one launch (z selects) -------
__global__ void tconv4(const float* __restrict__ wq, const float* __restrict__ wk,
                       const float* __restrict__ wv, const float* __restrict__ wfc,
                       bf16_t* __restrict__ wqT, bf16_t* __restrict__ wkT,
                       bf16_t* __restrict__ wvT, bf16_t* __restrict__ wfT) {
  __shared__ float t[32][33];
  const int z = blockIdx.z;
  const float* s; bf16_t* d; int R, C, c0, r0;
  if (z < 3) {
    s = (z == 0) ? wq : (z == 1) ? wk : wv;
    d = (z == 0) ? wqT : (z == 1) ? wkT : wvT;
    R = D_; C = HD_; c0 = blockIdx.x * 32; r0 = blockIdx.y * 32;
  } else {
    s = wfc; d = wfT;
    R = HD_; C = D_; c0 = blockIdx.y * 32; r0 = blockIdx.x * 32;
  }
  int tx = threadIdx.x, ty = threadIdx.y;
  #pragma unroll
  for (int i = 0; i < 32; i += 8)
    t[ty + i][tx] = s[(long)(r0 + ty + i) * C + c0 + tx];
  __syncthreads();
  #pragma unroll
  for (int i = 0; i < 32; i += 8)
    d[(long)(c0 + ty + i) * R + r0 + tx] = (bf16_t)t[tx][ty + i];
}

// ================= 256x256 8-phase GEMM, A(M,K) x Bt(N,K)^T =================
// EPI 0: bf16 store; EPI 1: f32 store;
// EPI 4: merged QKV — A selected per n-tile (qbf/kbf/vbf via sAb stride);
//        n-tile<16: qh (scaled), <32: kh, else vhT transposed store (Cv2).
#define VM4 asm volatile("s_waitcnt vmcnt(4)" ::: "memory")
#define VM0 asm volatile("s_waitcnt vmcnt(0)" ::: "memory")

#define STG(OP, BUF, KK, TILE) do { \
  const bf16_t* gsrc_ = (OP) ? Bg : Ag; \
  const long gld_ = (OP) ? ldb : lda; \
  bf16_t* lb_ = lds + (BUF)*32768 + (OP)*16384 + (KK)*8192 + wid*512; \
  gload_lds16(gsrc_ + (long)(TILE)*64 + (KK)*32, lb_); \
  gload_lds16(gsrc_ + (long)128*gld_ + (long)(TILE)*64 + (KK)*32, lb_ + 4096); \
} while (0)

#define LDA(I, BUF, KK) (*(const bf16x8*)(lds + (BUF)*32768 + (KK)*8192 + offA[I]))
#define LDB(J, BUF, KK) (*(const bf16x8*)(lds + (BUF)*32768 + 16384 + (KK)*8192 + offB[J]))

#define MM(q, ii, jj) acc[(q)*4+(ii)][(jj)] = \
  __builtin_amdgcn_mfma_f32_16x16x32_bf16(a##ii, b##jj, acc[(q)*4+(ii)][(jj)], 0, 0, 0)

#define PHASE(Q, KK, BUF, STAGE, VM) do { \
  bf16x8 a0, a1, a2, a3; \
  if ((Q) == 0) { b0 = LDB(0,BUF,KK); b1 = LDB(1,BUF,KK); b2 = LDB(2,BUF,KK); b3 = LDB(3,BUF,KK); } \
  a0 = LDA((Q)*4+0,BUF,KK); a1 = LDA((Q)*4+1,BUF,KK); \
  a2 = LDA((Q)*4+2,BUF,KK); a3 = LDA((Q)*4+3,BUF,KK); \
  STAGE; \
  __builtin_amdgcn_s_barrier(); \
  asm volatile("s_waitcnt lgkmcnt(0)" ::: "memory"); \
  __builtin_amdgcn_sched_barrier(0); \
  __builtin_amdgcn_s_setprio(1); \
  MM(Q,0,0); MM(Q,1,0); MM(Q,2,0); MM(Q,3,0); \
  MM(Q,0,1); MM(Q,1,1); MM(Q,2,1); MM(Q,3,1); \
  MM(Q,0,2); MM(Q,1,2); MM(Q,2,2); MM(Q,3,2); \
  MM(Q,0,3); MM(Q,1,3); MM(Q,2,3); MM(Q,3,3); \
  __builtin_amdgcn_s_setprio(0); \
  VM; \
  __builtin_amdgcn_s_barrier(); \
} while (0)

template<int EPI>
__launch_bounds__(512, 2)
__global__ void gemm256(const bf16_t* __restrict__ A, long sAb, long sAh, int lda,
                        const bf16_t* __restrict__ Bt, long sBb, long sBh, int ldb,
                        void* __restrict__ Cv, long sCb, long sCh, int ldc,
                        int K, float scale, void* __restrict__ Cv2)
{
  __shared__ __align__(16) bf16_t lds[65536];   // 128 KiB
  int tx, ty, tz;
  xcd_remap(tx, ty, tz);
  const int bz = tz, b = bz >> 3, h = bz & 7;
  if (EPI == 4) {
    A += (long)((tx >= 32) ? 2 : (tx >= 16) ? 1 : 0) * sAb;
  } else {
    A += (long)b * sAb + (long)h * sAh;
  }
  Bt += (long)b * sBb + (long)h * sBh;
  const int m0 = ty * 256, n0 = tx * 256;
  const int tid = threadIdx.x, lane = tid & 63, wid = tid >> 6;
  const int wm = wid >> 2, wn = wid & 3;

  const int srow  = tid >> 2;
  const int sslot = (lane & 3) ^ ((tid >> 3) & 3);
  const bf16_t* Ag = A + (long)(m0 + srow) * lda + sslot * 8;
  const bf16_t* Bg = Bt + (long)(n0 + srow) * ldb + sslot * 8;

  int offA[8], offB[4];
  #pragma unroll
  for (int i = 0; i < 8; ++i) {
    const int r = wm * 128 + i * 16 + (lane & 15);
    offA[i] = r * 32 + (((lane >> 4) ^ ((r >> 1) & 3)) * 8);
  }
  #pragma unroll
  for (int j = 0; j < 4; ++j) {
    const int r = wn * 64 + j * 16 + (lane & 15);
    offB[j] = r * 32 + (((lane >> 4) ^ ((r >> 1) & 3)) * 8);
  }

  f32x4 acc[8][4] = {};
  const int ITER = K >> 7;

  STG(0,0,0,0); STG(0,0,1,0); STG(1,0,0,0); STG(1,0,1,0);
  STG(0,1,0,1); STG(1,1,0,1);
  VM4;
  __builtin_amdgcn_s_barrier();

  for (int i = 0; i < ITER; ++i) {
    const int t = 2 * i;
    const bool stg = (i + 1 < ITER);
    bf16x8 b0, b1, b2, b3;
    PHASE(0,0,0, STG(0,1,1,t+1);                , (void)0);
    PHASE(1,0,0, STG(1,1,1,t+1);                , (void)0);
    PHASE(0,1,0, { if (stg) STG(0,0,0,t+2); }   , (void)0);
    PHASE(1,1,0, { if (stg) STG(1,0,0,t+2); }   , { if (stg) { VM4; } else { VM0; } });
    PHASE(0,0,1, { if (stg) STG(0,0,1,t+2); }   , (void)0);
    PHASE(1,0,1, { if (stg) STG(1,0,1,t+2); }   , (void)0);
    PHASE(0,1,1, { if (stg) STG(0,1,0,t+3); }   , (void)0);
    PHASE(1,1,1, { if (stg) STG(1,1,0,t+3); }   , { if (stg) { VM4; } });
  }

  const float sc = (EPI == 4 && tx >= 16) ? 1.0f : scale;
  const long coff = (long)b * sCb + (long)h * sCh;
  #pragma unroll
  for (int i = 0; i < 8; ++i) {
    const int rbase = m0 + wm * 128 + i * 16 + ((lane >> 4) << 2);
    #pragma unroll
    for (int j = 0; j < 4; ++j) {
      const int c = n0 + wn * 64 + j * 16 + (lane & 15);
      if (EPI == 4) {
        if (tx < 32) {          // q or k: linear bf16 store, ld = HD_
          bf16_t* dst = (bf16_t*)Cv + (tx >= 16 ? KOFF : 0);
          const int cc = c - (tx >= 16 ? 4096 : 0);
          #pragma unroll
          for (int r = 0; r < 4; ++r)
            dst[(long)(rbase + r) * HD_ + cc] = (bf16_t)(acc[i][j][r] * sc);
        } else {                // v: transposed per-(b,h) store into vhT
          const int cc = c - 8192;
          const int b2 = rbase >> 10, l2 = rbase & 1023;
          const int h2 = cc >> 9, d2 = cc & 511;
          bf16x4 o4;
          #pragma unroll
          for (int r = 0; r < 4; ++r) o4[r] = (bf16_t)acc[i][j][r];
          *(bf16x4*)((bf16_t*)Cv2 + (long)(b2 * 8 + h2) * D_ * L_ + (long)d2 * L_ + l2) = o4;
        }
      } else {
        #pragma unroll
        for (int r = 0; r < 4; ++r) {
          float vv = acc[i][j][r] * sc;
          long idx = coff + (long)(rbase + r) * ldc + c;
          if (EPI == 0) ((bf16_t*)Cv)[idx] = (bf16_t)vv;
          else          ((float*)Cv)[idx] = vv;
        }
      }
    }
  }
}

// ---------------- bf16 GEMM, 2-barrier, BMxBN tile (out-proj) ----------------
template<int BM, int BN, int EPI>
__launch_bounds__(256, 2)
__global__ void gemm_bt(const bf16_t* __restrict__ A, long sAb, long sAh, int lda,
                        const bf16_t* __restrict__ Bt, long sBb, long sBh, int ldb,
                        void* __restrict__ Cv, long sCb, long sCh, int ldc,
                        int K, float scale, const float* __restrict__ res)
{
  constexpr int WN    = (BN == 128) ? 2 : 1;
  constexpr int SPANM = BM / (4 / WN);
  constexpr int MI    = SPANM / 16;
  constexpr int NJ    = 4;
  __shared__ bf16_t sA[BM * 64];
  __shared__ bf16_t sB[BN * 64];
  int tx, ty, tz;
  xcd_remap(tx, ty, tz);
  const int bz = tz, b = bz >> 3, h = bz & 7;
  A  += (long)b * sAb + (long)h * sAh;
  Bt += (long)b * sBb + (long)h * sBh;
  const int m0 = ty * BM, n0 = tx * BN;
  const int tid = threadIdx.x, lane = tid & 63, wid = tid >> 6;
  const int waveM = (WN == 2) ? (wid >> 1) : wid;
  const int waveN = (WN == 2) ? (wid & 1) : 0;
  f32x4 acc[MI][NJ] = {};
  const int srow = wid * 8 + (lane >> 3);
  const int skin = (lane & 7) * 8;
  const bf16_t* Ag = A + (long)(m0 + srow) * lda + skin;
  const bf16_t* Bg = Bt + (long)(n0 + srow) * ldb + skin;
  for (int k0 = 0; k0 < K; k0 += 64) {
    #pragma unroll
    for (int j = 0; j < BM / 32; ++j)
      gload_lds16(Ag + (long)(j * 32) * lda + k0, sA + (j * 4 + wid) * 512);
    #pragma unroll
    for (int j = 0; j < BN / 32; ++j)
      gload_lds16(Bg + (long)(j * 32) * ldb + k0, sB + (j * 4 + wid) * 512);
    __syncthreads();
    #pragma unroll
    for (int kk = 0; kk < 2; ++kk) {
      bf16x8 af[MI], bfr[NJ];
      #pragma unroll
      for (int i = 0; i < MI; ++i)
        af[i]  = *(const bf16x8*)(sA + (waveM * SPANM + i * 16 + (lane & 15)) * 64 + kk * 32 + ((lane >> 4) * 8));
      #pragma unroll
      for (int j = 0; j < NJ; ++j)
        bfr[j] = *(const bf16x8*)(sB + (waveN * 64 + j * 16 + (lane & 15)) * 64 + kk * 32 + ((lane >> 4) * 8));
      #pragma unroll
      for (int i = 0; i < MI; ++i)
        #pragma unroll
        for (int j = 0; j < NJ; ++j)
          acc[i][j] = __builtin_amdgcn_mfma_f32_16x16x32_bf16(af[i], bfr[j], acc[i][j], 0, 0, 0);
    }
    __syncthreads();
  }
  const long coff = (long)b * sCb + (long)h * sCh;
  #pragma unroll
  for (int i = 0; i < MI; ++i) {
    const int rbase = m0 + waveM * SPANM + i * 16 + ((lane >> 4) << 2);
    #pragma unroll
    for (int j = 0; j < NJ; ++j) {
      const int c = n0 + waveN * 64 + j * 16 + (lane & 15);
      #pragma unroll
      for (int r = 0; r < 4; ++r) {
        float v = acc[i][j][r] * scale;
        long idx = coff + (long)(rbase + r) * ldc + c;
        if (EPI == 0)      ((bf16_t*)Cv)[idx] = (bf16_t)v;
        else if (EPI == 1) ((float*)Cv)[idx] = v;
        else               ((float*)Cv)[idx] = v + res[(long)(rbase + r) * ldc + c];
      }
    }
  }
}

// ------- softmax from bf16 raw scores: write f32 attn + bf16 P in place -------
__global__ void softmax_bf16(bf16_t* __restrict__ braw, float* __restrict__ attn) {
  const long row = (long)blockIdx.x * 4 + (threadIdx.x >> 6);
  const int lane = threadIdx.x & 63;
  bf16_t* p = braw + row * 1024;
  float* ao = attn + row * 1024;
  float v[16];
  float m = -1e30f;
  #pragma unroll
  for (int j = 0; j < 4; ++j) {
    bf16x4 x = *(const bf16x4*)(p + j * 256 + lane * 4);
    #pragma unroll
    for (int e = 0; e < 4; ++e) {
      v[j * 4 + e] = (float)x[e];
      m = fmaxf(m, v[j * 4 + e]);
    }
  }
  #pragma unroll
  for (int o = 32; o; o >>= 1) m = fmaxf(m, __shfl_xor(m, o));
  float s = 0.f;
  #pragma unroll
  for (int e = 0; e < 16; ++e) { v[e] = __expf(v[e] - m); s += v[e]; }
  #pragma unroll
  for (int o = 32; o; o >>= 1) s += __shfl_xor(s, o);
  const float inv = 1.f / s;
  #pragma unroll
  for (int j = 0; j < 4; ++j) {
    float4 f; bf16x4 o4;
    f.x = v[j*4+0] * inv; f.y = v[j*4+1] * inv;
    f.z = v[j*4+2] * inv; f.w = v[j*4+3] * inv;
    o4[0] = (bf16_t)f.x; o4[1] = (bf16_t)f.y; o4[2] = (bf16_t)f.z; o4[3] = (bf16_t)f.w;
    ((float4*)ao)[j * 64 + lane] = f;
    *(bf16x4*)(p + j * 256 + lane * 4) = o4;
  }
}

// ---------------- softmax from f32 scores (fallback path) ----------------
__global__ void softmax_rows(float* __restrict__ attn, bf16_t* __restrict__ abf) {
  const long row = (long)blockIdx.x * 4 + (threadIdx.x >> 6);
  const int lane = threadIdx.x & 63;
  float* p = attn + row * 1024;
  float4 v[4];
  float m = -1e30f;
  #pragma unroll
  for (int j = 0; j < 4; ++j) {
    v[j] = ((const float4*)p)[j * 64 + lane];
    m = fmaxf(m, fmaxf(fmaxf(v[j].x, v[j].y), fmaxf(v[j].z, v[j].w)));
  }
  #pragma unroll
  for (int o = 32; o; o >>= 1) m = fmaxf(m, __shfl_xor(m, o));
  float s = 0.f;
  #pragma unroll
  for (int j = 0; j < 4; ++j) {
    v[j].x = expf(v[j].x - m); v[j].y = expf(v[j].y - m);
    v[j].z = expf(v[j].z - m); v[j].w = expf(v[j].w - m);
    s += v[j].x + v[j].y + v[j].z + v[j].w;
  }
  #pragma unroll
  for (int o = 32; o; o >>= 1) s += __shfl_xor(s, o);
  const float inv = 1.f / s;
  bf16x4* ab = (bf16x4*)(abf + row * 1024);
  #pragma unroll
  for (int j = 0; j < 4; ++j) {
    v[j].x *= inv; v[j].y *= inv; v[j].z *= inv; v[j].w *= inv;
    ((float4*)p)[j * 64 + lane] = v[j];
    bf16x4 o4;
    o4[0] = (bf16_t)v[j].x; o4[1] = (bf16_t)v[j].y;
    o4[2] = (bf16_t)v[j].z; o4[3] = (bf16_t)v[j].w;
    ab[j * 64 + lane] = o4;
  }
}

// ---------------- LayerNorm: one wave per 512-col row, in-place ----------------
__global__ void ln_rows(float* __restrict__ o, const float* __restrict__ g,
                        const float* __restrict__ be) {
  const long row = (long)blockIdx.x * 4 + (threadIdx.x >> 6);
  const int lane = threadIdx.x & 63;
  float* p = o + row * 512;
  float4 a = ((const float4*)p)[lane];
  float4 b = ((const float4*)p)[lane + 64];
  float s  = a.x + a.y + a.z + a.w + b.x + b.y + b.z + b.w;
  float s2 = a.x*a.x + a.y*a.y + a.z*a.z + a.w*a.w
           + b.x*b.x + b.y*b.y + b.z*b.z + b.w*b.w;
  #pragma unroll
  for (int t = 32; t; t >>= 1) { s += __shfl_xor(s, t); s2 += __shfl_xor(s2, t); }
  const float mu  = s * (1.f / 512.f);
  const float var = s2 * (1.f / 512.f) - mu * mu;
  const float inv = rsqrtf(var + 1e-6f);
  float4 g0 = ((const float4*)g)[lane],  g1 = ((const float4*)g)[lane + 64];
  float4 b0 = ((const float4*)be)[lane], b1 = ((const float4*)be)[lane + 64];
  a.x = (a.x - mu) * inv * g0.x + b0.x;  a.y = (a.y - mu) * inv * g0.y + b0.y;
  a.z = (a.z - mu) * inv * g0.z + b0.z;  a.w = (a.w - mu) * inv * g0.w + b0.w;
  b.x = (b.x - mu) * inv * g1.x + b1.x;  b.y = (b.y - mu) * inv * g1.y + b1.y;
  b.z = (b.z - mu) * inv * g1.z + b1.z;  b.w = (b.w - mu) * inv * g1.w + b1.w;
  ((float4*)p)[lane] = a;
  ((float4*)p)[lane + 64] = b;
}

extern "C" void kernel_launch(void* const* d_in, const int* in_sizes, int n_in,
                              void* d_out, int out_size, void* d_ws, size_t ws_size,
                              hipStream_t stream) {
  const float* q   = (const float*)d_in[0];
  const float* k   = (const float*)d_in[1];
  const float* v   = (const float*)d_in[2];
  const float* wq  = (const float*)d_in[3];
  const float* wk  = (const float*)d_in[4];
  const float* wv  = (const float*)d_in[5];
  const float* wfc = (const float*)d_in[6];
  const float* lng = (const float*)d_in[7];
  const float* lnb = (const float*)d_in[8];

  float* out   = (float*)d_out;
  float* attnf = out + (long)BL_ * D_;   // attn output region (B,H,L,L) f32

  char* ws = (char*)d_ws;
  const long MB = 1024 * 1024;
  bf16_t* qbf = (bf16_t*)(ws +   0 * MB);   // qbf/kbf/vbf contiguous, 8 MiB each
  bf16_t* kbf = (bf16_t*)(ws +   8 * MB);
  bf16_t* vbf = (bf16_t*)(ws +  16 * MB);
  bf16_t* wqT = (bf16_t*)(ws +  24 * MB);   // wqT/wkT/wvT contiguous (12288 x 512)
  bf16_t* wkT = (bf16_t*)(ws +  28 * MB);
  bf16_t* wvT = (bf16_t*)(ws +  32 * MB);
  bf16_t* wfT = (bf16_t*)(ws +  36 * MB);
  bf16_t* qh  = (bf16_t*)(ws +  40 * MB);   // 64 MiB; kh = qh + KOFF
  bf16_t* kh  = (bf16_t*)(ws + 104 * MB);   // 64 MiB
  bf16_t* vh  = (bf16_t*)(ws + 168 * MB);   // 64 MiB (ctx)
  bf16_t* vhT = (bf16_t*)(ws + 232 * MB);   // 64 MiB
  bf16_t* ctx = vh;

  const bool fused = (ws_size >= (size_t)(424 * MB));
  bf16_t* braw = (bf16_t*)(ws + 296 * MB);  // 128 MiB raw scores / P (fused path)
  bf16_t* abf  = fused ? braw : qh;         // fallback P overlays qh+kh

  // 1) converts (2 launches)
  const int n4 = BL_ * D_ / 4;
  f2b3<<<dim3(n4 / 256, 3), 256, 0, stream>>>((const float4*)q, (const float4*)k,
                                              (const float4*)v, (bf16x4*)qbf,
                                              (bf16x4*)kbf, (bf16x4*)vbf, n4);
  tconv4<<<dim3(128, 16, 4), dim3(32, 8), 0, stream>>>(wq, wk, wv, wfc,
                                                       wqT, wkT, wvT, wfT);

  // 2) merged q/k/v projection: one launch, N=12288 (wqT|wkT|wvT stacked).
  const float qscale = 1.0f / sqrtf((float)D_);
  gemm256<4><<<dim3(48, 32, 1), 512, 0, stream>>>(qbf, 4194304L, 0, D_,
                                                  wqT, 0, 0, D_,
                                                  qh, 0, 0, HD_, D_, qscale, vhT);

  if (fused) {
    // 3) scores -> bf16 raw; softmax reads bf16, writes f32 attn + bf16 P in place
    gemm256<0><<<dim3(4, 4, B_ * H_), 512, 0, stream>>>(
        qh, (long)L_ * HD_, D_, HD_,
        kh, (long)L_ * HD_, D_, HD_,
        braw, (long)H_ * L_ * L_, (long)L_ * L_, L_, D_, 1.0f, nullptr);
    softmax_bf16<<<dim3(B_ * H_ * L_ / 4), 256, 0, stream>>>(braw, attnf);
  } else {
    gemm256<1><<<dim3(4, 4, B_ * H_), 512, 0, stream>>>(
        qh, (long)L_ * HD_, D_, HD_,
        kh, (long)L_ * HD_, D_, HD_,
        attnf, (long)H_ * L_ * L_, (long)L_ * L_, L_, D_, 1.0f, nullptr);
    softmax_rows<<<dim3(B_ * H_ * L_ / 4), 256, 0, stream>>>(attnf, abf);
  }

  // 4) ctx = P @ vhT^T per (b,h)
  gemm256<0><<<dim3(2, 4, B_ * H_), 512, 0, stream>>>(
      abf, (long)H_ * L_ * L_, (long)L_ * L_, L_,
      vhT, (long)H_ * D_ * L_, (long)D_ * L_, L_,
      ctx, (long)L_ * HD_, D_, HD_, L_, 1.0f, nullptr);

  // 5) out = ctx @ w_fc + residual(q), f32
  gemm_bt<128,64,2><<<dim3(8, 64, 1), 256, 0, stream>>>(
      ctx, 0, 0, HD_, wfT, 0, 0, HD_,
      out, 0, 0, D_, HD_, 1.0f, q);

  // 6) LayerNorm in place
  ln_rows<<<dim3(BL_ / 4), 256, 0, stream>>>(out, lng, lnb);
}